// Round 3
// baseline (1767.599 us; speedup 1.0000x reference)
//
#include <hip/hip_runtime.h>
#include <math.h>

#define F0 1433
#define F1 32
#define F2 7

// ---------------- degree / dinv ----------------
__global__ void k_init_deg(float* __restrict__ deg, int N) {
    int i = blockIdx.x * 256 + threadIdx.x;
    if (i < N) deg[i] = 1.0f;   // self-loop contributes 1
}

__global__ void k_count_deg(const int* __restrict__ dst, float* __restrict__ deg, int E) {
    int e = blockIdx.x * 256 + threadIdx.x;
    if (e < E) atomicAdd(&deg[dst[e]], 1.0f);
}

__global__ void k_dinv(float* __restrict__ deg, int N) {
    int i = blockIdx.x * 256 + threadIdx.x;
    if (i < N) deg[i] = rsqrtf(deg[i]);   // deg >= 1 always (self-loops)
}

// ---------------- GEMM1: h1[N,32] = x[N,1433] @ W1[1433,32] ----------------
// BM=128 rows, BK=32, 256 threads, thread tile 4 rows x 4 cols.
// DOUBLE-BUFFERED global_load_lds pipeline (2-phase): issue DMA for tile t+1,
// COMPUTE tile t, barrier (vmcnt drain lands after compute -> HBM latency
// hidden inside the block). LDS = 2*(16K + 4K) = 40960 B = exactly 4 blocks/CU.
// X staged at 4B width (rows only 4B-aligned: F0 odd); W at 16B width (4KiB
// tile stride keeps source 16B-aligned). Bank spreading via source-side XOR
// swizzle at float4 granularity, same XOR on the read side (both-sides rule):
// phys group = logical group ^ (row&7); read banks cover all 32, 8-way bcast.
// Per-wave 32-row chunk clamp handles the row tail (N must be mult of 32).
// Epilogue writes h1 and agg1 = h1*dinv^2 (fused self-loop term).
#define BM 128
#define BK 32
#define NT_FULL 44
#define KTAIL 1408

typedef const __attribute__((address_space(1))) void* gas_ptr;
typedef __attribute__((address_space(3))) void* las_ptr;

__device__ __forceinline__ void gl_lds4(const void* g, void* l) {
    __builtin_amdgcn_global_load_lds((gas_ptr)g, (las_ptr)l, 4, 0, 0);
}
__device__ __forceinline__ void gl_lds16(const void* g, void* l) {
    __builtin_amdgcn_global_load_lds((gas_ptr)g, (las_ptr)l, 16, 0, 0);
}

// issue DMA for one K-tile into buffer B; xb/wb advanced by caller
#define STAGE_DMA(B)                                                         \
    {                                                                        \
        _Pragma("unroll")                                                    \
        for (int it = 0; it < 16; ++it) {                                    \
            const float* p = xb + (size_t)((it >> 2) * (8 * F0)) + offm[it & 3]; \
            gl_lds4(p, &xs[B][(wv * 32 + it * 2) * BK]);                     \
        }                                                                    \
        gl_lds16(wb, &wsm[B][wv * 256]);                                     \
    }

#define COMPUTE(B)                                                           \
    _Pragma("unroll")                                                        \
    for (int kk = 0; kk < BK; kk += 4) {                                     \
        const int xo = (((kk >> 2) ^ key) << 2);                             \
        float4 x0 = *(const float4*)&xs[B][(r     ) * BK + xo];              \
        float4 x1 = *(const float4*)&xs[B][(r + 32) * BK + xo];              \
        float4 x2 = *(const float4*)&xs[B][(r + 64) * BK + xo];              \
        float4 x3 = *(const float4*)&xs[B][(r + 96) * BK + xo];              \
        const float a0[4] = {x0.x, x0.y, x0.z, x0.w};                        \
        const float a1[4] = {x1.x, x1.y, x1.z, x1.w};                        \
        const float a2[4] = {x2.x, x2.y, x2.z, x2.w};                        \
        const float a3[4] = {x3.x, x3.y, x3.z, x3.w};                        \
        _Pragma("unroll")                                                    \
        for (int u = 0; u < 4; ++u) {                                        \
            float4 w = *(const float4*)&wsm[B][(kk + u) * F1 + cg * 4];      \
            acc[0][0] += a0[u] * w.x; acc[0][1] += a0[u] * w.y;              \
            acc[0][2] += a0[u] * w.z; acc[0][3] += a0[u] * w.w;              \
            acc[1][0] += a1[u] * w.x; acc[1][1] += a1[u] * w.y;              \
            acc[1][2] += a1[u] * w.z; acc[1][3] += a1[u] * w.w;              \
            acc[2][0] += a2[u] * w.x; acc[2][1] += a2[u] * w.y;              \
            acc[2][2] += a2[u] * w.z; acc[2][3] += a2[u] * w.w;              \
            acc[3][0] += a3[u] * w.x; acc[3][1] += a3[u] * w.y;              \
            acc[3][2] += a3[u] * w.z; acc[3][3] += a3[u] * w.w;              \
        }                                                                    \
    }

__global__ __launch_bounds__(256) void k_gemm1(const float* __restrict__ x,
                                               const float* __restrict__ W,
                                               const float* __restrict__ dinv,
                                               float* __restrict__ h,
                                               float* __restrict__ agg, int N) {
    __shared__ float xs[2][BM * BK];    // 2 x 16384 B
    __shared__ float wsm[2][BK * F1];   // 2 x 4096 B  -> 40960 B total
    const int tid  = threadIdx.x;
    const int lane = tid & 63;
    const int wv   = tid >> 6;        // wave id 0..3
    const int row0 = blockIdx.x * BM;
    const int cg   = tid & 7;         // col group: cols cg*4..cg*4+3
    const int r    = tid >> 3;        // 0..31 -> rows r, r+32, r+64, r+96
    const int key  = r & 7;

    // ---- staging geometry (4B X DMA: 64 lanes = 2 rows of 32 floats) ----
    const int srow = lane >> 5;       // row within pair (0/1)
    const int scol = lane & 31;       // float within row
    // per-lane swizzled offsets for issue-index residues m = it&3
    // (row-in-tile = it*2 + srow; key period 4 in it since 8 | (it>>2)*8)
    int offm[4];
    #pragma unroll
    for (int m = 0; m < 4; ++m) {
        int rk = (2 * m + srow) & 7;
        offm[m] = (2 * m + srow) * F0 + ((((scol >> 2) ^ rk) << 2) | (scol & 3));
    }
    // per-wave 32-row chunk, clamped (N is a multiple of 32)
    int chunk0 = row0 + wv * 32;
    if (chunk0 > N - 32) chunk0 = N - 32;
    const float* xb = x + (size_t)chunk0 * F0;
    const float* wb = W + wv * 256 + lane * 4;   // 16B-aligned, stride 4KiB/tile

    float acc[4][4] = {{0.f, 0.f, 0.f, 0.f}, {0.f, 0.f, 0.f, 0.f},
                       {0.f, 0.f, 0.f, 0.f}, {0.f, 0.f, 0.f, 0.f}};

    STAGE_DMA(0)
    xb += BK; wb += BK * F1;
    __syncthreads();                 // drain: buf0 ready

    for (int t = 0; t < NT_FULL; ++t) {
        if (t + 1 < NT_FULL) {
            STAGE_DMA((t + 1) & 1)   // issue next tile, overlaps compute below
            xb += BK; wb += BK * F1;
        }
        COMPUTE(t & 1)
        __syncthreads();             // drains the DMA issued above; latency hidden
    }

    // ---- K tail: 25 valid cols, register-staged + predicated, into buf0 ----
    #pragma unroll
    for (int l = 0; l < 16; ++l) {
        int idx = tid + l * 256;     // 0..4095
        int row = idx >> 5, col = idx & 31;
        int gr = row0 + row, gk = KTAIL + col;
        float v = (gr < N && gk < F0) ? x[(size_t)gr * F0 + gk] : 0.f;
        xs[0][row * BK + ((((col >> 2) ^ (row & 7)) << 2) | (col & 3))] = v;
    }
    #pragma unroll
    for (int l = 0; l < 4; ++l) {
        int idx = tid + l * 256;     // 0..1023
        int gk = KTAIL + (idx >> 5);
        wsm[0][idx] = (gk < F0) ? W[(size_t)gk * F1 + (idx & 31)] : 0.f;
    }
    __syncthreads();
    COMPUTE(0)

    #pragma unroll
    for (int m = 0; m < 4; ++m) {
        int gr = row0 + r + 32 * m;
        if (gr < N) {
            float4 o = make_float4(acc[m][0], acc[m][1], acc[m][2], acc[m][3]);
            *(float4*)&h[(size_t)gr * F1 + cg * 4] = o;
            float d = dinv[gr];
            float dd = d * d;
            *(float4*)&agg[(size_t)gr * F1 + cg * 4] =
                make_float4(o.x * dd, o.y * dd, o.z * dd, o.w * dd);
        }
    }
}

// ---------------- layer-1 aggregation ----------------
// one thread per (edge, feature); 2 edges per wave
__global__ void k_scatter1(const int* __restrict__ src, const int* __restrict__ dst,
                           const float* __restrict__ dinv, const float* __restrict__ h1,
                           float* __restrict__ agg, int E) {
    int t = blockIdx.x * 256 + threadIdx.x;
    int e = t >> 5;
    if (e >= E) return;
    int f = t & 31;
    int s = src[e], d = dst[e];
    float w = dinv[s] * dinv[d];
    atomicAdd(&agg[d * F1 + f], h1[s * F1 + f] * w);
}

// ---------------- fused: ReLU(agg1+b1) @ W2 -> h2 ; out init = h2*dinv^2 ----------------
__global__ __launch_bounds__(256) void k_layer2(const float* __restrict__ agg1,
                                                const float* __restrict__ b1,
                                                const float* __restrict__ W2,
                                                const float* __restrict__ dinv,
                                                float* __restrict__ h2,
                                                float* __restrict__ out, int N) {
    __shared__ float w2s[F1 * F2];
    __shared__ float b1s[F1];
    int tid = threadIdx.x;
    if (tid < F1 * F2) w2s[tid] = W2[tid];
    if (tid < F1) b1s[tid] = b1[tid];
    __syncthreads();
    int i = blockIdx.x * 256 + tid;
    if (i >= N) return;
    float v[F1];
    #pragma unroll
    for (int u = 0; u < 8; ++u) {
        float4 t = *(const float4*)&agg1[(long)i * F1 + u * 4];
        v[u*4+0] = fmaxf(t.x + b1s[u*4+0], 0.f);
        v[u*4+1] = fmaxf(t.y + b1s[u*4+1], 0.f);
        v[u*4+2] = fmaxf(t.z + b1s[u*4+2], 0.f);
        v[u*4+3] = fmaxf(t.w + b1s[u*4+3], 0.f);
    }
    float o[F2] = {0.f, 0.f, 0.f, 0.f, 0.f, 0.f, 0.f};
    #pragma unroll
    for (int k = 0; k < F1; ++k) {
        float a = v[k];
        #pragma unroll
        for (int c = 0; c < F2; ++c) o[c] += a * w2s[k * F2 + c];
    }
    float di = dinv[i];
    float dd = di * di;
    #pragma unroll
    for (int c = 0; c < F2; ++c) {
        h2[(long)i * F2 + c] = o[c];
        out[(long)i * F2 + c] = o[c] * dd;
    }
}

// one thread per (edge, class); 8 lanes/edge (lane 7 idle)
__global__ void k_scatter2(const int* __restrict__ src, const int* __restrict__ dst,
                           const float* __restrict__ dinv, const float* __restrict__ h2,
                           float* __restrict__ out, int E) {
    int t = blockIdx.x * 256 + threadIdx.x;
    int e = t >> 3;
    int c = t & 7;
    if (e >= E || c >= F2) return;
    int s = src[e], d = dst[e];
    float w = dinv[s] * dinv[d];
    atomicAdd(&out[(long)d * F2 + c], h2[(long)s * F2 + c] * w);
}

// ---------------- +b2 then log_softmax, in place ----------------
__global__ void k_logsoftmax(float* __restrict__ out, const float* __restrict__ b2, int N) {
    int i = blockIdx.x * 256 + threadIdx.x;
    if (i >= N) return;
    float v[F2];
    float m = -1e30f;
    #pragma unroll
    for (int c = 0; c < F2; ++c) {
        v[c] = out[(long)i * F2 + c] + b2[c];
        m = fmaxf(m, v[c]);
    }
    float s = 0.f;
    #pragma unroll
    for (int c = 0; c < F2; ++c) s += expf(v[c] - m);
    float l = logf(s);
    #pragma unroll
    for (int c = 0; c < F2; ++c) out[(long)i * F2 + c] = v[c] - m - l;
}

extern "C" void kernel_launch(void* const* d_in, const int* in_sizes, int n_in,
                              void* d_out, int out_size, void* d_ws, size_t ws_size,
                              hipStream_t stream) {
    const float* x  = (const float*)d_in[0];
    const int*   ei = (const int*)d_in[1];
    const float* W1 = (const float*)d_in[2];
    const float* b1 = (const float*)d_in[3];
    const float* W2 = (const float*)d_in[4];
    const float* b2 = (const float*)d_in[5];
    float* out = (float*)d_out;

    const int N = in_sizes[0] / F0;      // 100000
    const int E = in_sizes[1] / 2;       // 3200000
    const int* src = ei;
    const int* dst = ei + E;

    // workspace layout (floats): dinv[N] | h1[N*32] (aliased by h2[N*7]) | agg1[N*32]
    float* ws   = (float*)d_ws;
    size_t o    = 0;
    float* dinv = ws;        o += (size_t)((N + 3) & ~3);
    float* h1   = ws + o;    o += (size_t)N * F1;
    float* agg1 = ws + o;    o += (size_t)N * F1;
    float* h2   = h1;        // h1 is dead after k_scatter1

    const int nb_N  = (N + 255) / 256;
    const int nb_E  = (E + 255) / 256;

    k_init_deg  <<<nb_N, 256, 0, stream>>>(dinv, N);
    k_count_deg <<<nb_E, 256, 0, stream>>>(dst, dinv, E);
    k_dinv      <<<nb_N, 256, 0, stream>>>(dinv, N);

    k_gemm1     <<<(N + BM - 1) / BM, 256, 0, stream>>>(x, W1, dinv, h1, agg1, N);

    k_scatter1  <<<((size_t)E * 32 + 255) / 256, 256, 0, stream>>>(src, dst, dinv, h1, agg1, E);

    k_layer2    <<<nb_N, 256, 0, stream>>>(agg1, b1, W2, dinv, h2, out, N);

    k_scatter2  <<<((size_t)E * 8 + 255) / 256, 256, 0, stream>>>(src, dst, dinv, h2, out, E);

    k_logsoftmax<<<nb_N, 256, 0, stream>>>(out, b2, N);
}